// Round 15
// baseline (263.601 us; speedup 1.0000x reference)
//
#include <hip/hip_runtime.h>

#define N_NODES 100000
#define N_EDGES 3200000
#define N_LBL   200000
#define C1 128
#define C2 64

// bucketing: nodes grouped by (node >> BSH), 128 nodes per bucket
#define BSH   7
#define NPB   128
#define NBKT  ((N_NODES + NPB - 1) / NPB)   // 782
#define NCB   500                            // edge chunks / k1 blocks
#define PPT   512                            // pair_place threads
#define CHUNK (N_EDGES / NCB)                // 6400 edges per chunk (exact)
#define CAP   4992                            // srcs slots per bucket (mean 4092, +14 sigma)

#define RS    136                            // f16 LDS row stride (128 + 8)

typedef _Float16 half8 __attribute__((ext_vector_type(8)));
typedef float    f32x4 __attribute__((ext_vector_type(4)));

__device__ __forceinline__ float4 f4add(float4 a, float4 b) {
    return make_float4(a.x + b.x, a.y + b.y, a.z + b.z, a.w + b.w);
}
__device__ __forceinline__ unsigned short f2bf(float f) {
    unsigned int u = __float_as_uint(f);
    u += 0x7fff + ((u >> 16) & 1);           // RNE
    return (unsigned short)(u >> 16);
}
__device__ __forceinline__ float bflo(unsigned int u) {
    return __uint_as_float(u << 16);
}
__device__ __forceinline__ float bfhi(unsigned int u) {
    return __uint_as_float(u & 0xffff0000u);
}
__device__ __forceinline__ void acc16(float* acc, uint4 v) {
    acc[0] += bflo(v.x); acc[1] += bfhi(v.x);
    acc[2] += bflo(v.y); acc[3] += bfhi(v.y);
    acc[4] += bflo(v.z); acc[5] += bfhi(v.z);
    acc[6] += bflo(v.w); acc[7] += bfhi(v.w);
}

// ---------------------------------------------------------------------------
// k1) bucketize edges — R15 DETERMINISTIC form: no global atomics, no memset,
//     no reservation. Block b LDS-sorts its 6400 edges by bucket and writes
//     them DENSE at pairs[b*CHUNK] (fully-coalesced uint4), plus its hist/lofs
//     rows (coalesced). k2 gathers per-bucket runs via the (hist,lofs) tables.
//     R14 evidence: k1/k2 are work-scale-invariant; cost was atomics+gaps+
//     scattered writes, not per-block throughput.
__global__ __launch_bounds__(PPT) void pair_place_kernel(const int* __restrict__ ei,
        int* __restrict__ hist_g, int* __restrict__ lofs_g,
        unsigned int* __restrict__ pairs) {
    __shared__ int hist[NBKT];                       // 3.1 KB
    __shared__ int lofs[NBKT];                       // 3.1 KB (block-local excl scan)
    __shared__ __align__(16) unsigned int sortbuf[CHUNK];  // 25.6 KB
    int tid = threadIdx.x;
    for (int i = tid; i < NBKT; i += PPT) hist[i] = 0;
    __syncthreads();
    int base = blockIdx.x * CHUNK;
    unsigned int pk[13]; int bkt[13]; int rnk[13];   // 12 vec + 1 tail
    int e0 = base + tid * 12;                        // 512*12 = 6144
    #pragma unroll
    for (int kk = 0; kk < 3; ++kk) {
        int4 sv = *(const int4*)(ei + e0 + kk * 4);
        int4 dv = *(const int4*)(ei + N_EDGES + e0 + kk * 4);
        int b0 = dv.x >> BSH, b1 = dv.y >> BSH;
        int b2 = dv.z >> BSH, b3 = dv.w >> BSH;
        bkt[kk * 4 + 0] = b0;
        pk[kk * 4 + 0] = ((unsigned int)(dv.x & (NPB - 1)) << 17) | (unsigned int)sv.x;
        rnk[kk * 4 + 0] = atomicAdd(&hist[b0], 1);
        bkt[kk * 4 + 1] = b1;
        pk[kk * 4 + 1] = ((unsigned int)(dv.y & (NPB - 1)) << 17) | (unsigned int)sv.y;
        rnk[kk * 4 + 1] = atomicAdd(&hist[b1], 1);
        bkt[kk * 4 + 2] = b2;
        pk[kk * 4 + 2] = ((unsigned int)(dv.z & (NPB - 1)) << 17) | (unsigned int)sv.z;
        rnk[kk * 4 + 2] = atomicAdd(&hist[b2], 1);
        bkt[kk * 4 + 3] = b3;
        pk[kk * 4 + 3] = ((unsigned int)(dv.w & (NPB - 1)) << 17) | (unsigned int)sv.w;
        rnk[kk * 4 + 3] = atomicAdd(&hist[b3], 1);
    }
    if (tid < 256) {                                 // tail: edges 6144..6399
        int e = base + 6144 + tid;
        int s = ei[e], d = ei[N_EDGES + e];
        int b = d >> BSH;
        bkt[12] = b;
        pk[12] = ((unsigned int)(d & (NPB - 1)) << 17) | (unsigned int)s;
        rnk[12] = atomicAdd(&hist[b], 1);
    }
    __syncthreads();
    // wave 0 excl-scans hist -> lofs (13 elems/lane; disjoint writes)
    if (tid < 64) {
        int beg = tid * 13;                          // 64*13 = 832 >= 782
        int en = min(beg + 13, NBKT);
        int s = 0;
        for (int i = beg; i < en; ++i) s += hist[i];
        int incl = s;
        #pragma unroll
        for (int off = 1; off < 64; off <<= 1) {
            int t = __shfl_up(incl, off);
            if (tid >= off) incl += t;
        }
        int excl = incl - s;
        for (int i = beg; i < en; ++i) {
            lofs[i] = excl;
            excl += hist[i];
        }
    }
    __syncthreads();
    // LDS scatter into bucket-sorted order
    #pragma unroll
    for (int k = 0; k < 12; ++k)
        sortbuf[lofs[bkt[k]] + rnk[k]] = pk[k];      // < CHUNK by construction
    if (tid < 256)
        sortbuf[lofs[bkt[12]] + rnk[12]] = pk[12];
    __syncthreads();
    // dense fully-coalesced copy-out + per-block tables (coalesced rows)
    uint4* pd = (uint4*)(pairs + base);
    const uint4* ps = (const uint4*)sortbuf;
    for (int j = tid; j < CHUNK / 4; j += PPT)       // 1600 uint4
        pd[j] = ps[j];
    for (int i = tid; i < NBKT; i += PPT) {
        hist_g[blockIdx.x * NBKT + i] = hist[i];
        lofs_g[blockIdx.x * NBKT + i] = lofs[i];
    }
}

// k2) per-bucket finish — R15: run-gather form. Bucket b's edges live as 500
//     runs pairs[t*CHUNK + lofs_g[t][b] .. +hist_g[t][b]). Two LDS-atomic
//     passes (count -> place); ranks need not persist (any interleave is a
//     valid permutation). LDS ~25 KB -> 5 blocks/CU (was 3).
__global__ __launch_bounds__(512) void bucket_finish_kernel(
        const unsigned int* __restrict__ pairs, const int* __restrict__ hist_g,
        const int* __restrict__ lofs_g, const float4* __restrict__ x,
        int* __restrict__ offs, int* __restrict__ ends, float* __restrict__ inv,
        float4* __restrict__ xs, int* __restrict__ srcs) {
    __shared__ int clen[NCB];                        // 2 KB
    __shared__ int cstart[NCB];                      // 2 KB
    __shared__ int deg[NPB];
    __shared__ int deg2[NPB];
    __shared__ int nstart[NPB];
    __shared__ int wsum2[2];
    __shared__ __align__(16) int ls[CAP];            // 19.5 KB srcs staging
    int tid = threadIdx.x;
    int b = blockIdx.x;
    int nbase = b << BSH;
    int eb = b * CAP;
    if (tid < NPB) { deg[tid] = 0; deg2[tid] = 0; }
    if (tid < NCB) {
        clen[tid] = hist_g[tid * NBKT + b];          // strided column reads,
        cstart[tid] = tid * CHUNK + lofs_g[tid * NBKT + b];  // latency-hidden
    }
    __syncthreads();
    // pass A: count per-node degrees
    if (tid < NCB) {
        int cs = cstart[tid], cl = clen[tid];
        for (int k = 0; k < cl; ++k) {
            int node = (int)((pairs[cs + k] >> 17) & 127u);
            atomicAdd(&deg[node], 1);
        }
    }
    __syncthreads();
    int v = 0, incl = 0;
    if (tid < NPB) {                                 // waves 0-1: scan 128 degrees
        int lane = tid & 63;
        v = deg[tid];
        incl = v;
        #pragma unroll
        for (int off = 1; off < 64; off <<= 1) {
            int t = __shfl_up(incl, off);
            if (lane >= off) incl += t;
        }
        if (lane == 63) wsum2[tid >> 6] = incl;
    }
    __syncthreads();
    if (tid < NPB) {
        int excl = incl - v + ((tid >= 64) ? wsum2[0] : 0);
        int start = eb + excl;
        nstart[tid] = start;
        int n = nbase + tid;
        if (n < N_NODES) {
            offs[n] = start;
            ends[n] = start + v;
            float iv = rsqrtf((float)(v + 1));
            inv[n] = iv;
            float4 xv = x[n];
            xv.x *= iv; xv.y *= iv; xv.z *= iv; xv.w *= iv;
            xs[n] = xv;
        }
    }
    __syncthreads();
    // pass B: place (re-read runs, L2-hot; rank via deg2)
    if (tid < NCB) {
        int cs = cstart[tid], cl = clen[tid];
        for (int k = 0; k < cl; ++k) {
            unsigned int p = pairs[cs + k];
            int node = (int)((p >> 17) & 127u);
            int rnk = atomicAdd(&deg2[node], 1);
            int lp = nstart[node] - eb + rnk;        // [0,cnt) by construction
            lp = min(lp, CAP - 1);                   // defensive
            ls[lp] = (int)(p & 0x1FFFFu);
        }
    }
    __syncthreads();
    int cnt = min(wsum2[0] + wsum2[1], CAP);
    int cnt4 = (cnt + 3) >> 2;                       // int4 stream-out (<=3 pad
    for (int i = tid; i < cnt4; i += 512)            //  ints stay inside CAP)
        ((int4*)(srcs + eb))[i] = ((const int4*)ls)[i];
}

// ---------------------------------------------------------------------------
// 3) fused agg1 + gemm1 + MFMA gemm2 (R7 form — unchanged).
__global__ __launch_bounds__(256) void agg1_gemm12_kernel(
        const float4* __restrict__ xs, const int* __restrict__ offs,
        const int* __restrict__ ends, const int* __restrict__ srcs,
        const float* __restrict__ inv, const float* __restrict__ W1,
        const float* __restrict__ b1, const float* __restrict__ W2,
        unsigned short* __restrict__ hs2b) {
    __shared__ float w1s[4 * C1];                    // 2 KB
    __shared__ float bs[C1];                         // 0.5 KB
    __shared__ _Float16 w2t[C2 * RS];                // 17 KB (W2^T: [n][k])
    __shared__ _Float16 rows[64 * RS];               // 17 KB (h1 f16: [node][k])
    int tid = threadIdx.x;
    int base = blockIdx.x * 64;
    w1s[tid] = W1[tid];                      // W1 is 512 floats, block is 256:
    w1s[tid + 256] = W1[tid + 256];          // each thread loads BOTH halves
    if (tid < C1) bs[tid] = b1[tid];
    // stage W2 transposed as f16: w2t[n][k] (coalesced global read)
    for (int i = tid; i < C1 * C2; i += 256) {
        int k = i >> 6, n = i & 63;
        w2t[n * RS + k] = (_Float16)W2[i];
    }
    // Phase 0: gather aggX for the block's 64 nodes (4 lanes/node, xs is
    // L2-resident 1.6 MB). Butterfly leaves the sum in all 4 lanes.
    int nd = tid >> 2, g = tid & 3;
    int n = base + nd;
    float4 acc0 = make_float4(0.f, 0.f, 0.f, 0.f);
    {
        if (n < N_NODES) {
            if (g == 0) acc0 = xs[n];
            int e = ends[n];
            for (int j = offs[n] + g; j < e; j += 4)
                acc0 = f4add(acc0, xs[srcs[j]]);
        }
        acc0.x += __shfl_xor(acc0.x, 1); acc0.y += __shfl_xor(acc0.y, 1);
        acc0.z += __shfl_xor(acc0.z, 1); acc0.w += __shfl_xor(acc0.w, 1);
        acc0.x += __shfl_xor(acc0.x, 2); acc0.y += __shfl_xor(acc0.y, 2);
        acc0.z += __shfl_xor(acc0.z, 2); acc0.w += __shfl_xor(acc0.w, 2);
    }
    __syncthreads();          // staging (w1s/bs/w2t) complete
    // Phase A: h1 rows -> LDS (f16). thread = (node nd, part g): c = g+4*cc
    {
        float s = (n < N_NODES) ? inv[n] : 0.f;
        float4 t = acc0;
        t.x *= s; t.y *= s; t.z *= s; t.w *= s;
        #pragma unroll 8
        for (int cc = 0; cc < 32; ++cc) {
            int c = g + 4 * cc;
            float h = t.x * w1s[c] + t.y * w1s[C1 + c] + t.z * w1s[2 * C1 + c]
                    + t.w * w1s[3 * C1 + c] + bs[c];
            rows[nd * RS + c] = (_Float16)fmaxf(h, 0.f);
        }
    }
    __syncthreads();
    // Phase B: MFMA. wave w owns node-tile [16w,16w+16); 4 col-tiles x 4 K-steps.
    {
        int w = tid >> 6, lane = tid & 63;
        int lm = lane & 15, lg = lane >> 4;
        f32x4 acc[4];
        #pragma unroll
        for (int ct = 0; ct < 4; ++ct) acc[ct] = (f32x4){0.f, 0.f, 0.f, 0.f};
        const _Float16* arow = &rows[(16 * w + lm) * RS + 8 * lg];
        #pragma unroll
        for (int ks = 0; ks < 4; ++ks) {
            half8 a = *(const half8*)(arow + 32 * ks);
            #pragma unroll
            for (int ct = 0; ct < 4; ++ct) {
                half8 b = *(const half8*)(&w2t[(16 * ct + lm) * RS + 8 * lg + 32 * ks]);
                acc[ct] = __builtin_amdgcn_mfma_f32_16x16x32_f16(a, b, acc[ct], 0, 0, 0);
            }
        }
        #pragma unroll
        for (int r = 0; r < 4; ++r) {
            int m = base + 16 * w + 4 * lg + r;      // C/D row
            if (m < N_NODES) {
                float s = inv[m];
                #pragma unroll
                for (int ct = 0; ct < 4; ++ct) {
                    hs2b[(size_t)m * C2 + 16 * ct + lm] = f2bf(acc[ct][r] * s);
                }
            }
        }
    }
}

// 4) agg2: R0's unified form — at the dual gather wall (6.6M 64B-line touches
//    @ ~7 TB/s AND 160 MB fetch @ ~2.88 TB/s). Do not touch.
__global__ void agg2_kernel(const unsigned short* __restrict__ hs2b,
                            const int* __restrict__ offs, const int* __restrict__ ends,
                            const int* __restrict__ srcs, const float* __restrict__ inv,
                            const float4* __restrict__ b2,
                            unsigned short* __restrict__ zb) {
    int gid = blockIdx.x * blockDim.x + threadIdx.x;
    int n = gid >> 6;
    if (n >= N_NODES) return;
    int lane = gid & 63;
    int q = lane & 7;           // 16B chunk (8 bf16 channels) within the row
    int g = lane >> 3;          // neighbor slot 0..7
    float acc[8] = {0.f, 0.f, 0.f, 0.f, 0.f, 0.f, 0.f, 0.f};
    if (g == 0) {
        acc16(acc, *((const uint4*)(hs2b + (size_t)n * C2) + q));
    }
    int e = ends[n];
    int j = offs[n] + g;
    for (; j + 8 < e; j += 16) {            // both j and j+8 valid
        int s0 = srcs[j];
        int s1 = srcs[j + 8];
        uint4 v0 = *((const uint4*)(hs2b + (size_t)s0 * C2) + q);
        uint4 v1 = *((const uint4*)(hs2b + (size_t)s1 * C2) + q);
        acc16(acc, v0);
        acc16(acc, v1);
    }
    if (j < e) {
        acc16(acc, *((const uint4*)(hs2b + (size_t)srcs[j] * C2) + q));
    }
    #pragma unroll
    for (int k = 0; k < 8; ++k) {
        acc[k] += __shfl_xor(acc[k], 8);
        acc[k] += __shfl_xor(acc[k], 16);
        acc[k] += __shfl_xor(acc[k], 32);
    }
    if (g == 0) {
        float s = inv[n];
        float4 b0 = b2[q * 2], b1v = b2[q * 2 + 1];
        float o0 = acc[0] * s + b0.x,  o1 = acc[1] * s + b0.y;
        float o2 = acc[2] * s + b0.z,  o3 = acc[3] * s + b0.w;
        float o4 = acc[4] * s + b1v.x, o5 = acc[5] * s + b1v.y;
        float o6 = acc[6] * s + b1v.z, o7 = acc[7] * s + b1v.w;
        uint4 w;
        w.x = (unsigned int)f2bf(o0) | ((unsigned int)f2bf(o1) << 16);
        w.y = (unsigned int)f2bf(o2) | ((unsigned int)f2bf(o3) << 16);
        w.z = (unsigned int)f2bf(o4) | ((unsigned int)f2bf(o5) << 16);
        w.w = (unsigned int)f2bf(o6) | ((unsigned int)f2bf(o7) << 16);
        ((uint4*)(zb + (size_t)n * C2))[q] = w;
    }
}

// 5) decode: logits[e] = dot(zb[a], zb[b])   (8 lanes/edge, bf16 rows)
__global__ void decode_kernel(const int* __restrict__ eli,
                              const unsigned short* __restrict__ zb,
                              float* __restrict__ out) {
    int gid = blockIdx.x * blockDim.x + threadIdx.x;
    int e = gid >> 3;
    if (e >= N_LBL) return;
    int q = gid & 7;
    int a = eli[e], b = eli[N_LBL + e];
    uint4 va = ((const uint4*)zb)[(size_t)a * 8 + q];
    uint4 vb = ((const uint4*)zb)[(size_t)b * 8 + q];
    float p = bflo(va.x) * bflo(vb.x) + bfhi(va.x) * bfhi(vb.x)
            + bflo(va.y) * bflo(vb.y) + bfhi(va.y) * bfhi(vb.y)
            + bflo(va.z) * bflo(vb.z) + bfhi(va.z) * bfhi(vb.z)
            + bflo(va.w) * bflo(vb.w) + bfhi(va.w) * bfhi(vb.w);
    p += __shfl_xor(p, 4);
    p += __shfl_xor(p, 2);
    p += __shfl_xor(p, 1);
    if (q == 0) out[e] = p;
}

extern "C" void kernel_launch(void* const* d_in, const int* in_sizes, int n_in,
                              void* d_out, int out_size, void* d_ws, size_t ws_size,
                              hipStream_t stream) {
    const float* x  = (const float*)d_in[0];
    const int*   ei = (const int*)d_in[1];
    const int*  eli = (const int*)d_in[2];
    const float* W1 = (const float*)d_in[3];
    const float* b1 = (const float*)d_in[4];
    const float* W2 = (const float*)d_in[5];
    const float* b2 = (const float*)d_in[6];
    float* out = (float*)d_out;

    // workspace layout (all 16B aligned). Total ~60 MB (ws is 256 MB).
    char* p = (char*)d_ws;
    int*   hist_g  = (int*)p;   p += (size_t)NCB * NBKT * 4;              // 1.56 MB
    int*   lofs_g  = (int*)p;   p += (size_t)NCB * NBKT * 4;              // 1.56 MB
    int*   offs    = (int*)p;   p += (size_t)N_NODES * 4;
    int*   ends    = (int*)p;   p += (size_t)N_NODES * 4;
    float* inv     = (float*)p; p += (size_t)N_NODES * 4;
    unsigned int* pairs = (unsigned int*)p; p += (size_t)NCB * CHUNK * 4; // 12.8 MB dense
    int*   srcs    = (int*)p;   p += (size_t)NBKT * CAP * 4;              // 15.6 MB
    float* xs      = (float*)p; p += (size_t)N_NODES * 16;
    unsigned short* hs2b = (unsigned short*)p; p += (size_t)N_NODES * C2 * 2; // 12.8 MB
    unsigned short* zb   = (unsigned short*)p; p += (size_t)N_NODES * C2 * 2; // 12.8 MB

    // 5 dispatches, no memset (no global atomics anywhere in the build)
    pair_place_kernel<<<NCB, PPT, 0, stream>>>(ei, hist_g, lofs_g, pairs);
    bucket_finish_kernel<<<NBKT, 512, 0, stream>>>(pairs, hist_g, lofs_g,
                                                   (const float4*)x,
                                                   offs, ends, inv, (float4*)xs, srcs);
    agg1_gemm12_kernel<<<(N_NODES + 63) / 64, 256, 0, stream>>>(
        (const float4*)xs, offs, ends, srcs, inv, W1, b1, W2, hs2b);
    agg2_kernel<<<((size_t)N_NODES * 64 + 255) / 256, 256, 0, stream>>>(
        hs2b, offs, ends, srcs, inv, (const float4*)b2, zb);
    decode_kernel<<<((size_t)N_LBL * 8 + 255) / 256, 256, 0, stream>>>(eli, zb, out);
}

// Round 16
// 215.486 us; speedup vs baseline: 1.2233x; 1.2233x over previous
//
#include <hip/hip_runtime.h>

#define N_NODES 100000
#define N_EDGES 3200000
#define N_LBL   200000
#define C1 128
#define C2 64

// bucketing: nodes grouped by (node >> BSH), 128 nodes per bucket
#define BSH   7
#define NPB   128
#define NBKT  ((N_NODES + NPB - 1) / NPB)   // 782
#define NCB   500                            // placing blocks (2/CU)
#define PPT   512                            // pair_place threads
#define CHUNK (N_EDGES / NCB)                // 6400 edges per block (exact)
#define CAP   4992                           // slots per bucket (mean 4092, +14 sigma)

#define RS    136                            // f16 LDS row stride (128 + 8)

typedef _Float16 half8 __attribute__((ext_vector_type(8)));
typedef float    f32x4 __attribute__((ext_vector_type(4)));

__device__ __forceinline__ float4 f4add(float4 a, float4 b) {
    return make_float4(a.x + b.x, a.y + b.y, a.z + b.z, a.w + b.w);
}
__device__ __forceinline__ unsigned short f2bf(float f) {
    unsigned int u = __float_as_uint(f);
    u += 0x7fff + ((u >> 16) & 1);           // RNE
    return (unsigned short)(u >> 16);
}
__device__ __forceinline__ float bflo(unsigned int u) {
    return __uint_as_float(u << 16);
}
__device__ __forceinline__ float bfhi(unsigned int u) {
    return __uint_as_float(u & 0xffff0000u);
}
__device__ __forceinline__ void acc16(float* acc, uint4 v) {
    acc[0] += bflo(v.x); acc[1] += bfhi(v.x);
    acc[2] += bflo(v.y); acc[3] += bfhi(v.y);
    acc[4] += bflo(v.z); acc[5] += bfhi(v.z);
    acc[6] += bflo(v.w); acc[7] += bfhi(v.w);
}

// ---------------------------------------------------------------------------
// k1) bucketize edges (R10 form — session best). LDS-sort + run-coalesced
//     copy-out; 12 edges/thread via int4 pair loads; atomic reservation.
//     NOTE (R15 lesson): this build order also produces an agg2-friendly
//     srcs order (agg2 FETCH 160 MB vs 298 MB with the deterministic k2).
__global__ __launch_bounds__(PPT) void pair_place_kernel(const int* __restrict__ ei,
        int* __restrict__ gcursor, unsigned int* __restrict__ pairs) {
    __shared__ int hist[NBKT];                       // 3.1 KB
    __shared__ int cur[NBKT];                        // 3.1 KB
    __shared__ int lofs[NBKT];                       // 3.1 KB (block-local excl scan)
    __shared__ unsigned int sortbuf[CHUNK];          // 25.6 KB (bucket-sorted pk)
    __shared__ unsigned short bkt16[CHUNK];          // 12.8 KB
    int tid = threadIdx.x;
    for (int i = tid; i < NBKT; i += PPT) hist[i] = 0;
    __syncthreads();
    int base = blockIdx.x * CHUNK;
    unsigned int pk[13]; int bkt[13]; int rnk[13];   // 12 vec + 1 tail
    int e0 = base + tid * 12;                        // 512*12 = 6144
    #pragma unroll
    for (int kk = 0; kk < 3; ++kk) {
        int4 sv = *(const int4*)(ei + e0 + kk * 4);
        int4 dv = *(const int4*)(ei + N_EDGES + e0 + kk * 4);
        int b0 = dv.x >> BSH, b1 = dv.y >> BSH;
        int b2 = dv.z >> BSH, b3 = dv.w >> BSH;
        bkt[kk * 4 + 0] = b0;
        pk[kk * 4 + 0] = ((unsigned int)(dv.x & (NPB - 1)) << 17) | (unsigned int)sv.x;
        rnk[kk * 4 + 0] = atomicAdd(&hist[b0], 1);
        bkt[kk * 4 + 1] = b1;
        pk[kk * 4 + 1] = ((unsigned int)(dv.y & (NPB - 1)) << 17) | (unsigned int)sv.y;
        rnk[kk * 4 + 1] = atomicAdd(&hist[b1], 1);
        bkt[kk * 4 + 2] = b2;
        pk[kk * 4 + 2] = ((unsigned int)(dv.z & (NPB - 1)) << 17) | (unsigned int)sv.z;
        rnk[kk * 4 + 2] = atomicAdd(&hist[b2], 1);
        bkt[kk * 4 + 3] = b3;
        pk[kk * 4 + 3] = ((unsigned int)(dv.w & (NPB - 1)) << 17) | (unsigned int)sv.w;
        rnk[kk * 4 + 3] = atomicAdd(&hist[b3], 1);
    }
    if (tid < 256) {                                 // tail: edges 6144..6399
        int e = base + 6144 + tid;
        int s = ei[e], d = ei[N_EDGES + e];
        int b = d >> BSH;
        bkt[12] = b;
        pk[12] = ((unsigned int)(d & (NPB - 1)) << 17) | (unsigned int)s;
        rnk[12] = atomicAdd(&hist[b], 1);
    }
    __syncthreads();
    // reserve global ranges (all threads, strided) ...
    for (int i = tid; i < NBKT; i += PPT) {
        int h = hist[i];
        cur[i] = h ? (i * CAP + atomicAdd(&gcursor[i], h)) : 0;
    }
    // ... while wave 0 excl-scans hist -> lofs (13 elems/lane; disjoint writes)
    if (tid < 64) {
        int beg = tid * 13;                          // 64*13 = 832 >= 782
        int en = min(beg + 13, NBKT);
        int s = 0;
        for (int i = beg; i < en; ++i) s += hist[i];
        int incl = s;
        #pragma unroll
        for (int off = 1; off < 64; off <<= 1) {
            int t = __shfl_up(incl, off);
            if (tid >= off) incl += t;
        }
        int excl = incl - s;
        for (int i = beg; i < en; ++i) {
            lofs[i] = excl;
            excl += hist[i];
        }
    }
    __syncthreads();
    // LDS scatter into bucket-sorted order
    #pragma unroll
    for (int k = 0; k < 12; ++k) {
        int p = lofs[bkt[k]] + rnk[k];               // < CHUNK by construction
        sortbuf[p] = pk[k];
        bkt16[p] = (unsigned short)bkt[k];
    }
    if (tid < 256) {
        int p = lofs[bkt[12]] + rnk[12];
        sortbuf[p] = pk[12];
        bkt16[p] = (unsigned short)bkt[12];
    }
    __syncthreads();
    // coalesced-run copy-out
    for (int j = tid; j < CHUNK; j += PPT) {
        int b = bkt16[j];
        int pos = cur[b] + (j - lofs[b]);
        pos = min(pos, NBKT * CAP - 1);              // defensive (stat. never)
        pairs[pos] = sortbuf[j];
    }
}

// k2) per-bucket finish (R10 form — session best). uint4 pair loads,
//     rank-in-register LDS atomics, staged srcs + int4 stream-out.
__global__ __launch_bounds__(512) void bucket_finish_kernel(
        const unsigned int* __restrict__ pairs, const int* __restrict__ gcursor,
        const float4* __restrict__ x, int* __restrict__ offs, int* __restrict__ ends,
        float* __restrict__ inv, float4* __restrict__ xs, int* __restrict__ srcs) {
    __shared__ int deg[NPB];
    __shared__ int nstart[NPB];
    __shared__ int wsum2[2];
    __shared__ __align__(16) int ls[CAP];            // 19.5 KB srcs staging
    int tid = threadIdx.x;
    int b = blockIdx.x;
    int nbase = b << BSH;
    int eb = b * CAP;
    int cnt = min(gcursor[b], CAP);                  // gcursor holds the COUNT
    if (tid < NPB) deg[tid] = 0;
    __syncthreads();
    unsigned int pk[12]; int rnk[12];                // 3 uint4 slots x 4
    const uint4* pv = (const uint4*)(pairs + eb);    // eb = b*CAP, 16B aligned
    #pragma unroll
    for (int kk = 0; kk < 3; ++kk) {
        int j4 = kk * 512 + tid;                     // uint4 index, < 1248
        if (kk < 2 || j4 < CAP / 4) {
            uint4 p4 = pv[j4];                       // may read past cnt (in-CAP, masked)
            int jb = j4 * 4;
            if (jb < cnt) {
                pk[kk * 4 + 0] = p4.x;
                rnk[kk * 4 + 0] = atomicAdd(&deg[p4.x >> 17], 1);
            }
            if (jb + 1 < cnt) {
                pk[kk * 4 + 1] = p4.y;
                rnk[kk * 4 + 1] = atomicAdd(&deg[p4.y >> 17], 1);
            }
            if (jb + 2 < cnt) {
                pk[kk * 4 + 2] = p4.z;
                rnk[kk * 4 + 2] = atomicAdd(&deg[p4.z >> 17], 1);
            }
            if (jb + 3 < cnt) {
                pk[kk * 4 + 3] = p4.w;
                rnk[kk * 4 + 3] = atomicAdd(&deg[p4.w >> 17], 1);
            }
        }
    }
    __syncthreads();
    int v = 0, incl = 0;
    if (tid < NPB) {                                 // waves 0-1: scan 128 degrees
        int lane = tid & 63;
        v = deg[tid];
        incl = v;
        #pragma unroll
        for (int off = 1; off < 64; off <<= 1) {
            int t = __shfl_up(incl, off);
            if (lane >= off) incl += t;
        }
        if (lane == 63) wsum2[tid >> 6] = incl;
    }
    __syncthreads();
    if (tid < NPB) {
        int excl = incl - v + ((tid >= 64) ? wsum2[0] : 0);
        int start = eb + excl;
        nstart[tid] = start;
        int n = nbase + tid;
        if (n < N_NODES) {
            offs[n] = start;
            ends[n] = start + v;
            float iv = rsqrtf((float)(v + 1));
            inv[n] = iv;
            float4 xv = x[n];
            xv.x *= iv; xv.y *= iv; xv.z *= iv; xv.w *= iv;
            xs[n] = xv;
        }
    }
    __syncthreads();
    #pragma unroll
    for (int kk = 0; kk < 3; ++kk) {
        int j4 = kk * 512 + tid;
        int jb = j4 * 4;
        #pragma unroll
        for (int u = 0; u < 4; ++u) {
            if (jb + u < cnt) {
                unsigned int p = pk[kk * 4 + u];
                int lp = nstart[p >> 17] - eb + rnk[kk * 4 + u];  // [0,cnt)
                lp = min(lp, CAP - 1);               // defensive
                ls[lp] = (int)(p & 0x1FFFFu);
            }
        }
    }
    __syncthreads();
    int cnt4 = (cnt + 3) >> 2;                       // int4 stream-out (may write
    for (int i = tid; i < cnt4; i += 512)            //  <=3 pad ints inside CAP)
        ((int4*)(srcs + eb))[i] = ((const int4*)ls)[i];
}

// ---------------------------------------------------------------------------
// 3) fused agg1 + gemm1 + MFMA gemm2 (R7 form — unchanged).
__global__ __launch_bounds__(256) void agg1_gemm12_kernel(
        const float4* __restrict__ xs, const int* __restrict__ offs,
        const int* __restrict__ ends, const int* __restrict__ srcs,
        const float* __restrict__ inv, const float* __restrict__ W1,
        const float* __restrict__ b1, const float* __restrict__ W2,
        unsigned short* __restrict__ hs2b) {
    __shared__ float w1s[4 * C1];                    // 2 KB
    __shared__ float bs[C1];                         // 0.5 KB
    __shared__ _Float16 w2t[C2 * RS];                // 17 KB (W2^T: [n][k])
    __shared__ _Float16 rows[64 * RS];               // 17 KB (h1 f16: [node][k])
    int tid = threadIdx.x;
    int base = blockIdx.x * 64;
    w1s[tid] = W1[tid];                      // W1 is 512 floats, block is 256:
    w1s[tid + 256] = W1[tid + 256];          // each thread loads BOTH halves
    if (tid < C1) bs[tid] = b1[tid];
    // stage W2 transposed as f16: w2t[n][k] (coalesced global read)
    for (int i = tid; i < C1 * C2; i += 256) {
        int k = i >> 6, n = i & 63;
        w2t[n * RS + k] = (_Float16)W2[i];
    }
    // Phase 0: gather aggX for the block's 64 nodes (4 lanes/node, xs is
    // L2-resident 1.6 MB). Butterfly leaves the sum in all 4 lanes.
    int nd = tid >> 2, g = tid & 3;
    int n = base + nd;
    float4 acc0 = make_float4(0.f, 0.f, 0.f, 0.f);
    {
        if (n < N_NODES) {
            if (g == 0) acc0 = xs[n];
            int e = ends[n];
            for (int j = offs[n] + g; j < e; j += 4)
                acc0 = f4add(acc0, xs[srcs[j]]);
        }
        acc0.x += __shfl_xor(acc0.x, 1); acc0.y += __shfl_xor(acc0.y, 1);
        acc0.z += __shfl_xor(acc0.z, 1); acc0.w += __shfl_xor(acc0.w, 1);
        acc0.x += __shfl_xor(acc0.x, 2); acc0.y += __shfl_xor(acc0.y, 2);
        acc0.z += __shfl_xor(acc0.z, 2); acc0.w += __shfl_xor(acc0.w, 2);
    }
    __syncthreads();          // staging (w1s/bs/w2t) complete
    // Phase A: h1 rows -> LDS (f16). thread = (node nd, part g): c = g+4*cc
    {
        float s = (n < N_NODES) ? inv[n] : 0.f;
        float4 t = acc0;
        t.x *= s; t.y *= s; t.z *= s; t.w *= s;
        #pragma unroll 8
        for (int cc = 0; cc < 32; ++cc) {
            int c = g + 4 * cc;
            float h = t.x * w1s[c] + t.y * w1s[C1 + c] + t.z * w1s[2 * C1 + c]
                    + t.w * w1s[3 * C1 + c] + bs[c];
            rows[nd * RS + c] = (_Float16)fmaxf(h, 0.f);
        }
    }
    __syncthreads();
    // Phase B: MFMA. wave w owns node-tile [16w,16w+16); 4 col-tiles x 4 K-steps.
    {
        int w = tid >> 6, lane = tid & 63;
        int lm = lane & 15, lg = lane >> 4;
        f32x4 acc[4];
        #pragma unroll
        for (int ct = 0; ct < 4; ++ct) acc[ct] = (f32x4){0.f, 0.f, 0.f, 0.f};
        const _Float16* arow = &rows[(16 * w + lm) * RS + 8 * lg];
        #pragma unroll
        for (int ks = 0; ks < 4; ++ks) {
            half8 a = *(const half8*)(arow + 32 * ks);
            #pragma unroll
            for (int ct = 0; ct < 4; ++ct) {
                half8 b = *(const half8*)(&w2t[(16 * ct + lm) * RS + 8 * lg + 32 * ks]);
                acc[ct] = __builtin_amdgcn_mfma_f32_16x16x32_f16(a, b, acc[ct], 0, 0, 0);
            }
        }
        #pragma unroll
        for (int r = 0; r < 4; ++r) {
            int m = base + 16 * w + 4 * lg + r;      // C/D row
            if (m < N_NODES) {
                float s = inv[m];
                #pragma unroll
                for (int ct = 0; ct < 4; ++ct) {
                    hs2b[(size_t)m * C2 + 16 * ct + lm] = f2bf(acc[ct][r] * s);
                }
            }
        }
    }
}

// 4) agg2: R0's unified form — at the dual gather wall (6.6M 64B-line touches
//    @ ~7 TB/s AND 160 MB fetch @ ~2.88 TB/s; 62.3us is within 4% of the
//    line-touch floor). Do not touch.
__global__ void agg2_kernel(const unsigned short* __restrict__ hs2b,
                            const int* __restrict__ offs, const int* __restrict__ ends,
                            const int* __restrict__ srcs, const float* __restrict__ inv,
                            const float4* __restrict__ b2,
                            unsigned short* __restrict__ zb) {
    int gid = blockIdx.x * blockDim.x + threadIdx.x;
    int n = gid >> 6;
    if (n >= N_NODES) return;
    int lane = gid & 63;
    int q = lane & 7;           // 16B chunk (8 bf16 channels) within the row
    int g = lane >> 3;          // neighbor slot 0..7
    float acc[8] = {0.f, 0.f, 0.f, 0.f, 0.f, 0.f, 0.f, 0.f};
    if (g == 0) {
        acc16(acc, *((const uint4*)(hs2b + (size_t)n * C2) + q));
    }
    int e = ends[n];
    int j = offs[n] + g;
    for (; j + 8 < e; j += 16) {            // both j and j+8 valid
        int s0 = srcs[j];
        int s1 = srcs[j + 8];
        uint4 v0 = *((const uint4*)(hs2b + (size_t)s0 * C2) + q);
        uint4 v1 = *((const uint4*)(hs2b + (size_t)s1 * C2) + q);
        acc16(acc, v0);
        acc16(acc, v1);
    }
    if (j < e) {
        acc16(acc, *((const uint4*)(hs2b + (size_t)srcs[j] * C2) + q));
    }
    #pragma unroll
    for (int k = 0; k < 8; ++k) {
        acc[k] += __shfl_xor(acc[k], 8);
        acc[k] += __shfl_xor(acc[k], 16);
        acc[k] += __shfl_xor(acc[k], 32);
    }
    if (g == 0) {
        float s = inv[n];
        float4 b0 = b2[q * 2], b1v = b2[q * 2 + 1];
        float o0 = acc[0] * s + b0.x,  o1 = acc[1] * s + b0.y;
        float o2 = acc[2] * s + b0.z,  o3 = acc[3] * s + b0.w;
        float o4 = acc[4] * s + b1v.x, o5 = acc[5] * s + b1v.y;
        float o6 = acc[6] * s + b1v.z, o7 = acc[7] * s + b1v.w;
        uint4 w;
        w.x = (unsigned int)f2bf(o0) | ((unsigned int)f2bf(o1) << 16);
        w.y = (unsigned int)f2bf(o2) | ((unsigned int)f2bf(o3) << 16);
        w.z = (unsigned int)f2bf(o4) | ((unsigned int)f2bf(o5) << 16);
        w.w = (unsigned int)f2bf(o6) | ((unsigned int)f2bf(o7) << 16);
        ((uint4*)(zb + (size_t)n * C2))[q] = w;
    }
}

// 5) decode: logits[e] = dot(zb[a], zb[b])   (8 lanes/edge, bf16 rows)
__global__ void decode_kernel(const int* __restrict__ eli,
                              const unsigned short* __restrict__ zb,
                              float* __restrict__ out) {
    int gid = blockIdx.x * blockDim.x + threadIdx.x;
    int e = gid >> 3;
    if (e >= N_LBL) return;
    int q = gid & 7;
    int a = eli[e], b = eli[N_LBL + e];
    uint4 va = ((const uint4*)zb)[(size_t)a * 8 + q];
    uint4 vb = ((const uint4*)zb)[(size_t)b * 8 + q];
    float p = bflo(va.x) * bflo(vb.x) + bfhi(va.x) * bfhi(vb.x)
            + bflo(va.y) * bflo(vb.y) + bfhi(va.y) * bfhi(vb.y)
            + bflo(va.z) * bflo(vb.z) + bfhi(va.z) * bfhi(vb.z)
            + bflo(va.w) * bflo(vb.w) + bfhi(va.w) * bfhi(vb.w);
    p += __shfl_xor(p, 4);
    p += __shfl_xor(p, 2);
    p += __shfl_xor(p, 1);
    if (q == 0) out[e] = p;
}

extern "C" void kernel_launch(void* const* d_in, const int* in_sizes, int n_in,
                              void* d_out, int out_size, void* d_ws, size_t ws_size,
                              hipStream_t stream) {
    const float* x  = (const float*)d_in[0];
    const int*   ei = (const int*)d_in[1];
    const int*  eli = (const int*)d_in[2];
    const float* W1 = (const float*)d_in[3];
    const float* b1 = (const float*)d_in[4];
    const float* W2 = (const float*)d_in[5];
    const float* b2 = (const float*)d_in[6];
    float* out = (float*)d_out;

    // workspace layout (all 16B aligned). Total ~59 MB.
    char* p = (char*)d_ws;
    int*   gcursor = (int*)p;   p += 1024 * 4;
    int*   offs    = (int*)p;   p += (size_t)N_NODES * 4;
    int*   ends    = (int*)p;   p += (size_t)N_NODES * 4;
    float* inv     = (float*)p; p += (size_t)N_NODES * 4;
    unsigned int* pairs = (unsigned int*)p; p += (size_t)NBKT * CAP * 4;  // 15.6 MB
    int*   srcs    = (int*)p;   p += (size_t)NBKT * CAP * 4;              // 15.6 MB
    float* xs      = (float*)p; p += (size_t)N_NODES * 16;
    unsigned short* hs2b = (unsigned short*)p; p += (size_t)N_NODES * C2 * 2; // 12.8 MB
    unsigned short* zb   = (unsigned short*)p; p += (size_t)N_NODES * C2 * 2; // 12.8 MB

    (void)hipMemsetAsync(gcursor, 0, NBKT * 4, stream);
    pair_place_kernel<<<NCB, PPT, 0, stream>>>(ei, gcursor, pairs);
    bucket_finish_kernel<<<NBKT, 512, 0, stream>>>(pairs, gcursor, (const float4*)x,
                                                   offs, ends, inv, (float4*)xs, srcs);
    agg1_gemm12_kernel<<<(N_NODES + 63) / 64, 256, 0, stream>>>(
        (const float4*)xs, offs, ends, srcs, inv, W1, b1, W2, hs2b);
    agg2_kernel<<<((size_t)N_NODES * 64 + 255) / 256, 256, 0, stream>>>(
        hs2b, offs, ends, srcs, inv, (const float4*)b2, zb);
    decode_kernel<<<((size_t)N_LBL * 8 + 255) / 256, 256, 0, stream>>>(eli, zb, out);
}

// Round 18
// 211.898 us; speedup vs baseline: 1.2440x; 1.0169x over previous
//
#include <hip/hip_runtime.h>

#define N_NODES 100000
#define N_EDGES 3200000
#define N_LBL   200000
#define C1 128
#define C2 64

// bucketing: nodes grouped by (node >> BSH), 128 nodes per bucket
#define BSH   7
#define NPB   128
#define NBKT  ((N_NODES + NPB - 1) / NPB)   // 782
#define NCB   500                            // placing blocks (2/CU)
#define PPT   512                            // pair_place threads
#define CHUNK (N_EDGES / NCB)                // 6400 edges per block (exact)
#define CAP   4992                           // slots per bucket (mean 4092, +14 sigma)

#define RS    136                            // f16 LDS row stride (128 + 8)

typedef _Float16 half8 __attribute__((ext_vector_type(8)));
typedef float    f32x4 __attribute__((ext_vector_type(4)));

__device__ __forceinline__ float4 f4add(float4 a, float4 b) {
    return make_float4(a.x + b.x, a.y + b.y, a.z + b.z, a.w + b.w);
}
__device__ __forceinline__ unsigned short f2bf(float f) {
    unsigned int u = __float_as_uint(f);
    u += 0x7fff + ((u >> 16) & 1);           // RNE
    return (unsigned short)(u >> 16);
}
__device__ __forceinline__ float bflo(unsigned int u) {
    return __uint_as_float(u << 16);
}
__device__ __forceinline__ float bfhi(unsigned int u) {
    return __uint_as_float(u & 0xffff0000u);
}
__device__ __forceinline__ void acc16(float* acc, uint4 v) {
    acc[0] += bflo(v.x); acc[1] += bfhi(v.x);
    acc[2] += bflo(v.y); acc[3] += bfhi(v.y);
    acc[4] += bflo(v.z); acc[5] += bfhi(v.z);
    acc[6] += bflo(v.w); acc[7] += bfhi(v.w);
}

// ---------------------------------------------------------------------------
// k1) bucketize edges (R10 form — session best, final). LDS-sort +
//     run-coalesced copy-out; 12 edges/thread via int4 pair loads; atomic
//     reservation. This build order also produces the agg2-friendly srcs
//     order (R15: deterministic variant doubled agg2's FETCH).
__global__ __launch_bounds__(PPT) void pair_place_kernel(const int* __restrict__ ei,
        int* __restrict__ gcursor, unsigned int* __restrict__ pairs) {
    __shared__ int hist[NBKT];                       // 3.1 KB
    __shared__ int cur[NBKT];                        // 3.1 KB
    __shared__ int lofs[NBKT];                       // 3.1 KB (block-local excl scan)
    __shared__ unsigned int sortbuf[CHUNK];          // 25.6 KB (bucket-sorted pk)
    __shared__ unsigned short bkt16[CHUNK];          // 12.8 KB
    int tid = threadIdx.x;
    for (int i = tid; i < NBKT; i += PPT) hist[i] = 0;
    __syncthreads();
    int base = blockIdx.x * CHUNK;
    unsigned int pk[13]; int bkt[13]; int rnk[13];   // 12 vec + 1 tail
    int e0 = base + tid * 12;                        // 512*12 = 6144
    #pragma unroll
    for (int kk = 0; kk < 3; ++kk) {
        int4 sv = *(const int4*)(ei + e0 + kk * 4);
        int4 dv = *(const int4*)(ei + N_EDGES + e0 + kk * 4);
        int b0 = dv.x >> BSH, b1 = dv.y >> BSH;
        int b2 = dv.z >> BSH, b3 = dv.w >> BSH;
        bkt[kk * 4 + 0] = b0;
        pk[kk * 4 + 0] = ((unsigned int)(dv.x & (NPB - 1)) << 17) | (unsigned int)sv.x;
        rnk[kk * 4 + 0] = atomicAdd(&hist[b0], 1);
        bkt[kk * 4 + 1] = b1;
        pk[kk * 4 + 1] = ((unsigned int)(dv.y & (NPB - 1)) << 17) | (unsigned int)sv.y;
        rnk[kk * 4 + 1] = atomicAdd(&hist[b1], 1);
        bkt[kk * 4 + 2] = b2;
        pk[kk * 4 + 2] = ((unsigned int)(dv.z & (NPB - 1)) << 17) | (unsigned int)sv.z;
        rnk[kk * 4 + 2] = atomicAdd(&hist[b2], 1);
        bkt[kk * 4 + 3] = b3;
        pk[kk * 4 + 3] = ((unsigned int)(dv.w & (NPB - 1)) << 17) | (unsigned int)sv.w;
        rnk[kk * 4 + 3] = atomicAdd(&hist[b3], 1);
    }
    if (tid < 256) {                                 // tail: edges 6144..6399
        int e = base + 6144 + tid;
        int s = ei[e], d = ei[N_EDGES + e];
        int b = d >> BSH;
        bkt[12] = b;
        pk[12] = ((unsigned int)(d & (NPB - 1)) << 17) | (unsigned int)s;
        rnk[12] = atomicAdd(&hist[b], 1);
    }
    __syncthreads();
    // reserve global ranges (all threads, strided) ...
    for (int i = tid; i < NBKT; i += PPT) {
        int h = hist[i];
        cur[i] = h ? (i * CAP + atomicAdd(&gcursor[i], h)) : 0;
    }
    // ... while wave 0 excl-scans hist -> lofs (13 elems/lane; disjoint writes)
    if (tid < 64) {
        int beg = tid * 13;                          // 64*13 = 832 >= 782
        int en = min(beg + 13, NBKT);
        int s = 0;
        for (int i = beg; i < en; ++i) s += hist[i];
        int incl = s;
        #pragma unroll
        for (int off = 1; off < 64; off <<= 1) {
            int t = __shfl_up(incl, off);
            if (tid >= off) incl += t;
        }
        int excl = incl - s;
        for (int i = beg; i < en; ++i) {
            lofs[i] = excl;
            excl += hist[i];
        }
    }
    __syncthreads();
    // LDS scatter into bucket-sorted order
    #pragma unroll
    for (int k = 0; k < 12; ++k) {
        int p = lofs[bkt[k]] + rnk[k];               // < CHUNK by construction
        sortbuf[p] = pk[k];
        bkt16[p] = (unsigned short)bkt[k];
    }
    if (tid < 256) {
        int p = lofs[bkt[12]] + rnk[12];
        sortbuf[p] = pk[12];
        bkt16[p] = (unsigned short)bkt[12];
    }
    __syncthreads();
    // coalesced-run copy-out
    for (int j = tid; j < CHUNK; j += PPT) {
        int b = bkt16[j];
        int pos = cur[b] + (j - lofs[b]);
        pos = min(pos, NBKT * CAP - 1);              // defensive (stat. never)
        pairs[pos] = sortbuf[j];
    }
}

// k2) per-bucket finish (R10 form — session best, final). uint4 pair loads,
//     rank-in-register LDS atomics, staged srcs + int4 stream-out.
__global__ __launch_bounds__(512) void bucket_finish_kernel(
        const unsigned int* __restrict__ pairs, const int* __restrict__ gcursor,
        const float4* __restrict__ x, int* __restrict__ offs, int* __restrict__ ends,
        float* __restrict__ inv, float4* __restrict__ xs, int* __restrict__ srcs) {
    __shared__ int deg[NPB];
    __shared__ int nstart[NPB];
    __shared__ int wsum2[2];
    __shared__ __align__(16) int ls[CAP];            // 19.5 KB srcs staging
    int tid = threadIdx.x;
    int b = blockIdx.x;
    int nbase = b << BSH;
    int eb = b * CAP;
    int cnt = min(gcursor[b], CAP);                  // gcursor holds the COUNT
    if (tid < NPB) deg[tid] = 0;
    __syncthreads();
    unsigned int pk[12]; int rnk[12];                // 3 uint4 slots x 4
    const uint4* pv = (const uint4*)(pairs + eb);    // eb = b*CAP, 16B aligned
    #pragma unroll
    for (int kk = 0; kk < 3; ++kk) {
        int j4 = kk * 512 + tid;                     // uint4 index, < 1248
        if (kk < 2 || j4 < CAP / 4) {
            uint4 p4 = pv[j4];                       // may read past cnt (in-CAP, masked)
            int jb = j4 * 4;
            if (jb < cnt) {
                pk[kk * 4 + 0] = p4.x;
                rnk[kk * 4 + 0] = atomicAdd(&deg[p4.x >> 17], 1);
            }
            if (jb + 1 < cnt) {
                pk[kk * 4 + 1] = p4.y;
                rnk[kk * 4 + 1] = atomicAdd(&deg[p4.y >> 17], 1);
            }
            if (jb + 2 < cnt) {
                pk[kk * 4 + 2] = p4.z;
                rnk[kk * 4 + 2] = atomicAdd(&deg[p4.z >> 17], 1);
            }
            if (jb + 3 < cnt) {
                pk[kk * 4 + 3] = p4.w;
                rnk[kk * 4 + 3] = atomicAdd(&deg[p4.w >> 17], 1);
            }
        }
    }
    __syncthreads();
    int v = 0, incl = 0;
    if (tid < NPB) {                                 // waves 0-1: scan 128 degrees
        int lane = tid & 63;
        v = deg[tid];
        incl = v;
        #pragma unroll
        for (int off = 1; off < 64; off <<= 1) {
            int t = __shfl_up(incl, off);
            if (lane >= off) incl += t;
        }
        if (lane == 63) wsum2[tid >> 6] = incl;
    }
    __syncthreads();
    if (tid < NPB) {
        int excl = incl - v + ((tid >= 64) ? wsum2[0] : 0);
        int start = eb + excl;
        nstart[tid] = start;
        int n = nbase + tid;
        if (n < N_NODES) {
            offs[n] = start;
            ends[n] = start + v;
            float iv = rsqrtf((float)(v + 1));
            inv[n] = iv;
            float4 xv = x[n];
            xv.x *= iv; xv.y *= iv; xv.z *= iv; xv.w *= iv;
            xs[n] = xv;
        }
    }
    __syncthreads();
    #pragma unroll
    for (int kk = 0; kk < 3; ++kk) {
        int j4 = kk * 512 + tid;
        int jb = j4 * 4;
        #pragma unroll
        for (int u = 0; u < 4; ++u) {
            if (jb + u < cnt) {
                unsigned int p = pk[kk * 4 + u];
                int lp = nstart[p >> 17] - eb + rnk[kk * 4 + u];  // [0,cnt)
                lp = min(lp, CAP - 1);               // defensive
                ls[lp] = (int)(p & 0x1FFFFu);
            }
        }
    }
    __syncthreads();
    int cnt4 = (cnt + 3) >> 2;                       // int4 stream-out (may write
    for (int i = tid; i < cnt4; i += 512)            //  <=3 pad ints inside CAP)
        ((int4*)(srcs + eb))[i] = ((const int4*)ls)[i];
}

// ---------------------------------------------------------------------------
// 3) fused agg1 + gemm1 + MFMA gemm2 (R7 form — final).
__global__ __launch_bounds__(256) void agg1_gemm12_kernel(
        const float4* __restrict__ xs, const int* __restrict__ offs,
        const int* __restrict__ ends, const int* __restrict__ srcs,
        const float* __restrict__ inv, const float* __restrict__ W1,
        const float* __restrict__ b1, const float* __restrict__ W2,
        unsigned short* __restrict__ hs2b) {
    __shared__ float w1s[4 * C1];                    // 2 KB
    __shared__ float bs[C1];                         // 0.5 KB
    __shared__ _Float16 w2t[C2 * RS];                // 17 KB (W2^T: [n][k])
    __shared__ _Float16 rows[64 * RS];               // 17 KB (h1 f16: [node][k])
    int tid = threadIdx.x;
    int base = blockIdx.x * 64;
    w1s[tid] = W1[tid];                      // W1 is 512 floats, block is 256:
    w1s[tid + 256] = W1[tid + 256];          // each thread loads BOTH halves
    if (tid < C1) bs[tid] = b1[tid];
    // stage W2 transposed as f16: w2t[n][k] (coalesced global read)
    for (int i = tid; i < C1 * C2; i += 256) {
        int k = i >> 6, n = i & 63;
        w2t[n * RS + k] = (_Float16)W2[i];
    }
    // Phase 0: gather aggX for the block's 64 nodes (4 lanes/node, xs is
    // L2-resident 1.6 MB). Butterfly leaves the sum in all 4 lanes.
    int nd = tid >> 2, g = tid & 3;
    int n = base + nd;
    float4 acc0 = make_float4(0.f, 0.f, 0.f, 0.f);
    {
        if (n < N_NODES) {
            if (g == 0) acc0 = xs[n];
            int e = ends[n];
            for (int j = offs[n] + g; j < e; j += 4)
                acc0 = f4add(acc0, xs[srcs[j]]);
        }
        acc0.x += __shfl_xor(acc0.x, 1); acc0.y += __shfl_xor(acc0.y, 1);
        acc0.z += __shfl_xor(acc0.z, 1); acc0.w += __shfl_xor(acc0.w, 1);
        acc0.x += __shfl_xor(acc0.x, 2); acc0.y += __shfl_xor(acc0.y, 2);
        acc0.z += __shfl_xor(acc0.z, 2); acc0.w += __shfl_xor(acc0.w, 2);
    }
    __syncthreads();          // staging (w1s/bs/w2t) complete
    // Phase A: h1 rows -> LDS (f16). thread = (node nd, part g): c = g+4*cc
    {
        float s = (n < N_NODES) ? inv[n] : 0.f;
        float4 t = acc0;
        t.x *= s; t.y *= s; t.z *= s; t.w *= s;
        #pragma unroll 8
        for (int cc = 0; cc < 32; ++cc) {
            int c = g + 4 * cc;
            float h = t.x * w1s[c] + t.y * w1s[C1 + c] + t.z * w1s[2 * C1 + c]
                    + t.w * w1s[3 * C1 + c] + bs[c];
            rows[nd * RS + c] = (_Float16)fmaxf(h, 0.f);
        }
    }
    __syncthreads();
    // Phase B: MFMA. wave w owns node-tile [16w,16w+16); 4 col-tiles x 4 K-steps.
    {
        int w = tid >> 6, lane = tid & 63;
        int lm = lane & 15, lg = lane >> 4;
        f32x4 acc[4];
        #pragma unroll
        for (int ct = 0; ct < 4; ++ct) acc[ct] = (f32x4){0.f, 0.f, 0.f, 0.f};
        const _Float16* arow = &rows[(16 * w + lm) * RS + 8 * lg];
        #pragma unroll
        for (int ks = 0; ks < 4; ++ks) {
            half8 a = *(const half8*)(arow + 32 * ks);
            #pragma unroll
            for (int ct = 0; ct < 4; ++ct) {
                half8 b = *(const half8*)(&w2t[(16 * ct + lm) * RS + 8 * lg + 32 * ks]);
                acc[ct] = __builtin_amdgcn_mfma_f32_16x16x32_f16(a, b, acc[ct], 0, 0, 0);
            }
        }
        #pragma unroll
        for (int r = 0; r < 4; ++r) {
            int m = base + 16 * w + 4 * lg + r;      // C/D row
            if (m < N_NODES) {
                float s = inv[m];
                #pragma unroll
                for (int ct = 0; ct < 4; ++ct) {
                    hs2b[(size_t)m * C2 + 16 * ct + lm] = f2bf(acc[ct][r] * s);
                }
            }
        }
    }
}

// 4) agg2: R0's unified form — at the dual gather wall (6.6M 64B-line touches
//    @ ~7 TB/s AND 160 MB fetch @ ~2.88 TB/s; 62.3us is within 4% of the
//    line-touch floor). Final.
__global__ void agg2_kernel(const unsigned short* __restrict__ hs2b,
                            const int* __restrict__ offs, const int* __restrict__ ends,
                            const int* __restrict__ srcs, const float* __restrict__ inv,
                            const float4* __restrict__ b2,
                            unsigned short* __restrict__ zb) {
    int gid = blockIdx.x * blockDim.x + threadIdx.x;
    int n = gid >> 6;
    if (n >= N_NODES) return;
    int lane = gid & 63;
    int q = lane & 7;           // 16B chunk (8 bf16 channels) within the row
    int g = lane >> 3;          // neighbor slot 0..7
    float acc[8] = {0.f, 0.f, 0.f, 0.f, 0.f, 0.f, 0.f, 0.f};
    if (g == 0) {
        acc16(acc, *((const uint4*)(hs2b + (size_t)n * C2) + q));
    }
    int e = ends[n];
    int j = offs[n] + g;
    for (; j + 8 < e; j += 16) {            // both j and j+8 valid
        int s0 = srcs[j];
        int s1 = srcs[j + 8];
        uint4 v0 = *((const uint4*)(hs2b + (size_t)s0 * C2) + q);
        uint4 v1 = *((const uint4*)(hs2b + (size_t)s1 * C2) + q);
        acc16(acc, v0);
        acc16(acc, v1);
    }
    if (j < e) {
        acc16(acc, *((const uint4*)(hs2b + (size_t)srcs[j] * C2) + q));
    }
    #pragma unroll
    for (int k = 0; k < 8; ++k) {
        acc[k] += __shfl_xor(acc[k], 8);
        acc[k] += __shfl_xor(acc[k], 16);
        acc[k] += __shfl_xor(acc[k], 32);
    }
    if (g == 0) {
        float s = inv[n];
        float4 b0 = b2[q * 2], b1v = b2[q * 2 + 1];
        float o0 = acc[0] * s + b0.x,  o1 = acc[1] * s + b0.y;
        float o2 = acc[2] * s + b0.z,  o3 = acc[3] * s + b0.w;
        float o4 = acc[4] * s + b1v.x, o5 = acc[5] * s + b1v.y;
        float o6 = acc[6] * s + b1v.z, o7 = acc[7] * s + b1v.w;
        uint4 w;
        w.x = (unsigned int)f2bf(o0) | ((unsigned int)f2bf(o1) << 16);
        w.y = (unsigned int)f2bf(o2) | ((unsigned int)f2bf(o3) << 16);
        w.z = (unsigned int)f2bf(o4) | ((unsigned int)f2bf(o5) << 16);
        w.w = (unsigned int)f2bf(o6) | ((unsigned int)f2bf(o7) << 16);
        ((uint4*)(zb + (size_t)n * C2))[q] = w;
    }
}

// 5) decode: logits[e] = dot(zb[a], zb[b])   (8 lanes/edge, bf16 rows)
__global__ void decode_kernel(const int* __restrict__ eli,
                              const unsigned short* __restrict__ zb,
                              float* __restrict__ out) {
    int gid = blockIdx.x * blockDim.x + threadIdx.x;
    int e = gid >> 3;
    if (e >= N_LBL) return;
    int q = gid & 7;
    int a = eli[e], b = eli[N_LBL + e];
    uint4 va = ((const uint4*)zb)[(size_t)a * 8 + q];
    uint4 vb = ((const uint4*)zb)[(size_t)b * 8 + q];
    float p = bflo(va.x) * bflo(vb.x) + bfhi(va.x) * bfhi(vb.x)
            + bflo(va.y) * bflo(vb.y) + bfhi(va.y) * bfhi(vb.y)
            + bflo(va.z) * bflo(vb.z) + bfhi(va.z) * bfhi(vb.z)
            + bflo(va.w) * bflo(vb.w) + bfhi(va.w) * bfhi(vb.w);
    p += __shfl_xor(p, 4);
    p += __shfl_xor(p, 2);
    p += __shfl_xor(p, 1);
    if (q == 0) out[e] = p;
}

extern "C" void kernel_launch(void* const* d_in, const int* in_sizes, int n_in,
                              void* d_out, int out_size, void* d_ws, size_t ws_size,
                              hipStream_t stream) {
    const float* x  = (const float*)d_in[0];
    const int*   ei = (const int*)d_in[1];
    const int*  eli = (const int*)d_in[2];
    const float* W1 = (const float*)d_in[3];
    const float* b1 = (const float*)d_in[4];
    const float* W2 = (const float*)d_in[5];
    const float* b2 = (const float*)d_in[6];
    float* out = (float*)d_out;

    // workspace layout (all 16B aligned). Total ~59 MB.
    char* p = (char*)d_ws;
    int*   gcursor = (int*)p;   p += 1024 * 4;
    int*   offs    = (int*)p;   p += (size_t)N_NODES * 4;
    int*   ends    = (int*)p;   p += (size_t)N_NODES * 4;
    float* inv     = (float*)p; p += (size_t)N_NODES * 4;
    unsigned int* pairs = (unsigned int*)p; p += (size_t)NBKT * CAP * 4;  // 15.6 MB
    int*   srcs    = (int*)p;   p += (size_t)NBKT * CAP * 4;              // 15.6 MB
    float* xs      = (float*)p; p += (size_t)N_NODES * 16;
    unsigned short* hs2b = (unsigned short*)p; p += (size_t)N_NODES * C2 * 2; // 12.8 MB
    unsigned short* zb   = (unsigned short*)p; p += (size_t)N_NODES * C2 * 2; // 12.8 MB

    (void)hipMemsetAsync(gcursor, 0, NBKT * 4, stream);
    pair_place_kernel<<<NCB, PPT, 0, stream>>>(ei, gcursor, pairs);
    bucket_finish_kernel<<<NBKT, 512, 0, stream>>>(pairs, gcursor, (const float4*)x,
                                                   offs, ends, inv, (float4*)xs, srcs);
    agg1_gemm12_kernel<<<(N_NODES + 63) / 64, 256, 0, stream>>>(
        (const float4*)xs, offs, ends, srcs, inv, W1, b1, W2, hs2b);
    agg2_kernel<<<((size_t)N_NODES * 64 + 255) / 256, 256, 0, stream>>>(
        hs2b, offs, ends, srcs, inv, (const float4*)b2, zb);
    decode_kernel<<<((size_t)N_LBL * 8 + 255) / 256, 256, 0, stream>>>(eli, zb, out);
}